// Round 20
// baseline (460.239 us; speedup 1.0000x reference)
//
#include <hip/hip_runtime.h>
#include <math.h>

#define KCODES 1024
#define DDIM   256
#define HWSZ   1024
#define CHW    262144
#define LOSS_OFF 16777216
#define IDX_OFF  16777217
#define TAU_GAP  1.4e-4f
#define RR8      8

// ---- path A: ws byte offsets ----
#define WS_ZH   0u          // 33554432 B (32MB)
#define WS_EH   33554432u
#define WS_EL   34078720u
#define WS_AN   34603008u
#define WS_BN   34865152u
#define WS_LIST 34869248u
#define WS_CNT  35131392u
#define WS_NEED 35131396u

// ---- path B: out-region offsets (f32 words) ----
#define OB_ZH   0
#define OB_EH   8388608
#define OB_EL   8519680
#define OB_AN   8650752
#define OB_BN   8716288
#define OB_LIST 8717312
#define OB_CNT  8782848

typedef __attribute__((ext_vector_type(8))) short short8v;
typedef __attribute__((ext_vector_type(4))) float float4v;

#define GLOAD_LDS(gsrc, ldst)                                                   \
    __builtin_amdgcn_global_load_lds(                                           \
        (const __attribute__((address_space(1))) void*)(gsrc),                  \
        (__attribute__((address_space(3))) void*)(ldst), 16, 0, 0)

static __device__ __forceinline__ unsigned short bf16_rne(float f) {
    unsigned u = __float_as_uint(f);
    return (unsigned short)((u + 0x7FFFu + ((u >> 16) & 1u)) >> 16);
}
static __device__ __forceinline__ float bf16_tf(unsigned short h) {
    return __uint_as_float(((unsigned)h) << 16);
}

// ---- Bn = ||e_k||^2 (ref pairwise order) + zero cnt/loss ------------------
__global__ __launch_bounds__(64) void vq_prep_bn(const float* __restrict__ emb,
                                                 float* __restrict__ Bn,
                                                 float* __restrict__ loss_slot,
                                                 int* __restrict__ cnt) {
    int k = blockIdx.x * 64 + threadIdx.x;
    if (k == 0) { *cnt = 0; loss_slot[0] = 0.f; }
    if (k >= KCODES) return;
    const float* e = emb + (size_t)k * DDIM;
    float half[2];
    #pragma unroll
    for (int h = 0; h < 2; ++h) {
        const float* q = e + (h << 7);
        float r[8];
        #pragma unroll
        for (int j = 0; j < 8; ++j) r[j] = __fmul_rn(q[j], q[j]);
        for (int i = 8; i < 128; i += 8) {
            #pragma unroll
            for (int j = 0; j < 8; ++j)
                r[j] = __fadd_rn(r[j], __fmul_rn(q[i + j], q[i + j]));
        }
        half[h] = __fadd_rn(
            __fadd_rn(__fadd_rn(r[0], r[1]), __fadd_rn(r[2], r[3])),
            __fadd_rn(__fadd_rn(r[4], r[5]), __fadd_rn(r[6], r[7])));
    }
    Bn[k] = __fadd_rn(half[0], half[1]);
}

// ---- E hi/lo fragment scatter (layout proven r5-r19) ----------------------
__global__ __launch_bounds__(256) void vq_prep_scatter(const float* __restrict__ emb,
                                                       unsigned short* __restrict__ EHg,
                                                       unsigned short* __restrict__ ELg) {
    int task = blockIdx.x * 256 + threadIdx.x;
    int k  = task >> 5;
    int dg = task & 31;
    const float* e = emb + (size_t)k * DDIM + (dg << 3);
    float4 v0 = *(const float4*)e;
    float4 v1 = *(const float4*)(e + 4);
    float f[8] = {v0.x, v0.y, v0.z, v0.w, v1.x, v1.y, v1.z, v1.w};
    short8v hv, lv;
    #pragma unroll
    for (int j = 0; j < 8; ++j) {
        unsigned short hb = bf16_rne(f[j]);
        unsigned short lb = bf16_rne(f[j] - bf16_tf(hb));
        hv[j] = (short)hb; lv[j] = (short)lb;
    }
    int base = ((k >> 4) << 12) + ((dg >> 2) << 9) + (((k & 15) + ((dg & 3) << 4)) << 3);
    *(short8v*)(EHg + base) = hv;
    *(short8v*)(ELg + base) = lv;
}

// ---- fused: An (bit-exact numpy order) + Zh fragment-order pre-convert ----
__global__ __launch_bounds__(256) void vq_zprep2(const float* __restrict__ z,
                                                 unsigned short* __restrict__ ZHg,
                                                 float* __restrict__ An) {
    __shared__ float hs[2][128];
    const int t = threadIdx.x;
    const int nb = blockIdx.x;
    const int b = nb >> 3, hw0 = (nb & 7) << 7;
    const int h = t >> 7, n = t & 127;
    const float* src = z + (size_t)b * CHW + (size_t)(h << 7) * HWSZ + hw0 + n;
    unsigned short* zbase = ZHg + (size_t)nb * 32768 + ((n >> 4) << 9) + ((n & 15) << 3);
    float r[8];
    #pragma unroll
    for (int blk8 = 0; blk8 < 16; ++blk8) {
        float f[8];
        #pragma unroll
        for (int j = 0; j < 8; ++j) f[j] = src[(size_t)((blk8 << 3) + j) * HWSZ];
        if (blk8 == 0) {
            #pragma unroll
            for (int j = 0; j < 8; ++j) r[j] = __fmul_rn(f[j], f[j]);
        } else {
            #pragma unroll
            for (int j = 0; j < 8; ++j) r[j] = __fadd_rn(r[j], __fmul_rn(f[j], f[j]));
        }
        short8v hv;
        #pragma unroll
        for (int j = 0; j < 8; ++j) hv[j] = (short)bf16_rne(f[j]);
        int d = (h << 7) + (blk8 << 3);
        int s32 = d >> 5, g = (d >> 3) & 3;
        *(short8v*)(zbase + s32 * 4096 + (g << 7)) = hv;
    }
    hs[h][n] = __fadd_rn(
        __fadd_rn(__fadd_rn(r[0], r[1]), __fadd_rn(r[2], r[3])),
        __fadd_rn(__fadd_rn(r[4], r[5]), __fadd_rn(r[6], r[7])));
    __syncthreads();
    if (t < 128) An[nb * 128 + t] = __fadd_rn(hs[0][t], hs[1][t]);
}

// ---- main: 2-term MFMA GEMM (Eh+El)xZh + top-2 argmin, 44KB LDS,
//      staging via async global_load_lds (r13/r16 champion, byte-identical) -
template<bool WRITE_OUT>
__global__ __launch_bounds__(512, 4) void vq_argmin2g(
        const unsigned short* __restrict__ ZHg,
        const unsigned short* __restrict__ EHg, const unsigned short* __restrict__ ELg,
        const float* __restrict__ An, const float* __restrict__ Bn,
        float* __restrict__ idx_out, int* __restrict__ list, int* __restrict__ cnt,
        float* __restrict__ loss_slot, float* __restrict__ outp,
        const float* __restrict__ emb) {
    __shared__ uint4 ZH4[512];
    __shared__ uint4 EBUF4[2048];
    __shared__ float BNs[1024];
    unsigned short* ZH = (unsigned short*)ZH4;
    unsigned short* EH = (unsigned short*)EBUF4;
    unsigned short* EL = EH + 8192;

    const int t = threadIdx.x;
    const int bid = blockIdx.x;
    const int nb = ((bid & 7) << 6) + (bid >> 3);
    const int b   = nb >> 3;
    const int hw0 = (nb & 7) << 7;
    const int lane = t & 63, w = t >> 6;
    const int kwv = w >> 1, nwv = w & 1;
    const int l8 = lane << 3, g2 = lane >> 4;

    BNs[t] = Bn[t];
    BNs[t + 512] = Bn[t + 512];

    float an[4];
    #pragma unroll
    for (int nf = 0; nf < 4; ++nf)
        an[nf] = An[nb * 128 + nwv * 64 + nf * 16 + (lane & 15)];

    float mv1[4], mv2[4]; int mi1[4];
    #pragma unroll
    for (int i = 0; i < 4; ++i) { mv1[i] = 3.4e38f; mv2[i] = 3.4e38f; mi1[i] = 0x7fffffff; }

    const uint4* zh4 = (const uint4*)ZHg + (size_t)nb * 4096;
    const uint4* eh4 = (const uint4*)EHg;
    const uint4* el4 = (const uint4*)ELg;

    for (int kt = 0; kt < 4; ++kt) {
        float4v acc[4][4];
        #pragma unroll
        for (int a = 0; a < 4; ++a)
            #pragma unroll
            for (int c = 0; c < 4; ++c) acc[a][c] = (float4v){0.f, 0.f, 0.f, 0.f};

        for (int s32 = 0; s32 < 8; ++s32) {
            __syncthreads();
            GLOAD_LDS(zh4 + s32 * 512 + t, &ZH4[t]);
            #pragma unroll
            for (int p = 0; p < 4; ++p) {
                int s = p * 512 + t;
                int arr = s >> 10, ss = s & 1023;
                const uint4* src = (arr ? el4 : eh4)
                    + (size_t)(((kt << 4) + (ss >> 6)) << 9) + (s32 << 6) + (ss & 63);
                uint4* dst = (arr ? ((uint4*)EL) : ((uint4*)EH)) + ss;
                GLOAD_LDS(src, dst);
            }
            __syncthreads();
            short8v ah[4], al[4], bh[4];
            #pragma unroll
            for (int kf = 0; kf < 4; ++kf) {
                int base = ((kwv * 4 + kf) << 9) + l8;
                ah[kf] = *(const short8v*)&EH[base];
                al[kf] = *(const short8v*)&EL[base];
            }
            #pragma unroll
            for (int nf = 0; nf < 4; ++nf)
                bh[nf] = *(const short8v*)&ZH[((nwv * 4 + nf) << 9) + l8];
            #pragma unroll
            for (int kf = 0; kf < 4; ++kf)
                #pragma unroll
                for (int nf = 0; nf < 4; ++nf) {
                    acc[kf][nf] = __builtin_amdgcn_mfma_f32_16x16x32_bf16(ah[kf], bh[nf], acc[kf][nf], 0, 0, 0);
                    acc[kf][nf] = __builtin_amdgcn_mfma_f32_16x16x32_bf16(al[kf], bh[nf], acc[kf][nf], 0, 0, 0);
                }
        }
        #pragma unroll
        for (int kf = 0; kf < 4; ++kf)
            #pragma unroll
            for (int nf = 0; nf < 4; ++nf)
                #pragma unroll
                for (int r = 0; r < 4; ++r) {
                    int k = kt * 256 + kwv * 64 + kf * 16 + g2 * 4 + r;
                    float s = __fsub_rn(__fadd_rn(an[nf], BNs[k]),
                                        __fmul_rn(2.0f, acc[kf][nf][r]));
                    if (s < mv1[nf] || (s == mv1[nf] && k < mi1[nf])) {
                        mv2[nf] = fminf(mv2[nf], mv1[nf]);
                        mv1[nf] = s; mi1[nf] = k;
                    } else if (s < mv2[nf]) mv2[nf] = s;
                }
    }

    __syncthreads();
    float* REDv = (float*)EBUF4;
    int*   REDi = (int*)((char*)EBUF4 + 8192);
    float* REDw = (float*)((char*)EBUF4 + 16384);
    int*   FIDX = (int*)((char*)EBUF4 + 24576);

    #pragma unroll
    for (int nf = 0; nf < 4; ++nf) {
        int nl = nf * 16 + (lane & 15);
        int slot = kwv * 4 + g2;
        REDv[(nwv * 64 + nl) * 16 + slot] = mv1[nf];
        REDi[(nwv * 64 + nl) * 16 + slot] = mi1[nf];
        REDw[(nwv * 64 + nl) * 16 + slot] = mv2[nf];
    }
    __syncthreads();
    if (t < 128) {
        float bv = 3.4e38f, b2 = 3.4e38f; int bi = 0x7fffffff;
        #pragma unroll
        for (int s = 0; s < 16; ++s) {
            float v1 = REDv[t * 16 + s];
            float v2 = REDw[t * 16 + s];
            int   i1 = REDi[t * 16 + s];
            if (v1 < bv || (v1 == bv && i1 < bi)) { b2 = fminf(b2, bv); bv = v1; bi = i1; }
            else b2 = fminf(b2, v1);
            b2 = fminf(b2, v2);
        }
        int n_glob = nb * 128 + t;
        idx_out[n_glob] = (float)bi;
        FIDX[t] = bi;
        if (b2 - bv < TAU_GAP) {
            int pos = atomicAdd(cnt, 1);
            list[pos] = n_glob;
        }
        float lsum = bv;
        #pragma unroll
        for (int off = 32; off > 0; off >>= 1)
            lsum += __shfl_down(lsum, off, 64);
        if ((t & 63) == 0) atomicAdd(loss_slot, lsum * (1.25f / 16777216.f));
    }
    if (WRITE_OUT) {
        __syncthreads();
        int n_loc = t & 127, cg = t >> 7;
        int idx = FIDX[n_loc];
        int hw = hw0 + n_loc;
        const float4* erow = (const float4*)(emb + (size_t)idx * DDIM + (cg << 6));
        float* obase = outp + (size_t)b * CHW + (size_t)(cg << 6) * HWSZ + hw;
        #pragma unroll 4
        for (int q = 0; q < 16; ++q) {
            float4 v = erow[q];
            obase[(size_t)(q * 4 + 0) * HWSZ] = v.x;
            obase[(size_t)(q * 4 + 1) * HWSZ] = v.y;
            obase[(size_t)(q * 4 + 2) * HWSZ] = v.z;
            obase[(size_t)(q * 4 + 3) * HWSZ] = v.w;
        }
    }
}

// ---- f64 rescore, 8 rows/block: halves sweep count vs RR4 -----------------
template<bool WRITE_OUT>
__global__ __launch_bounds__(512) void vq_rescore8(
        const float* __restrict__ z, const float* __restrict__ emb,
        const float* __restrict__ An, const float* __restrict__ Bn,
        float* __restrict__ idx_out, const int* __restrict__ list,
        const int* __restrict__ cnt, float* __restrict__ outp) {
    const int c = *cnt;
    const int t = threadIdx.x;
    const int lane = t & 63, w = t >> 6;   // 8 waves
    const int g  = lane >> 4;              // group 0..3 (one code each)
    const int ch = lane & 15;              // d-chunk within group
    __shared__ float zs[RR8][256];
    __shared__ float Ars[RR8];
    __shared__ int   rid[RR8];
    __shared__ float wsv[RR8][8];
    __shared__ int   wsi[RR8][8];
    __shared__ int   wbi[RR8];

    for (int base = blockIdx.x * RR8; base < c; base += gridDim.x * RR8) {
        const int nrows = min(RR8, c - base);
        __syncthreads();
        if (t < nrows) { int n = list[base + t]; rid[t] = n; Ars[t] = An[n]; }
        __syncthreads();
        for (int i = t; i < (nrows << 8); i += 512) {
            int r = i >> 8, d = i & 255;
            int n = rid[r];
            zs[r][d] = z[(size_t)(n >> 10) * CHW + (size_t)d * HWSZ + (n & 1023)];
        }
        __syncthreads();

        float bv[RR8]; int bi[RR8];
        #pragma unroll
        for (int r = 0; r < RR8; ++r) { bv[r] = 3.4e38f; bi[r] = 0x7fffffff; }

        for (int p = 0; p < 32; ++p) {          // ascending codes
            int cc = p * 32 + w * 4 + g;
            const float4* e4 = (const float4*)(emb + (size_t)cc * DDIM);
            double part[RR8];
            #pragma unroll
            for (int r = 0; r < RR8; ++r) part[r] = 0.0;
            #pragma unroll
            for (int it = 0; it < 4; ++it) {
                float4 ev = e4[it * 16 + ch];
                #pragma unroll
                for (int r = 0; r < RR8; ++r) {
                    float4 zv = *(const float4*)&zs[r][(it * 16 + ch) << 2];
                    part[r] += (double)ev.x * zv.x + (double)ev.y * zv.y
                             + (double)ev.z * zv.z + (double)ev.w * zv.w;
                }
            }
            #pragma unroll
            for (int off = 1; off <= 8; off <<= 1)
                #pragma unroll
                for (int r = 0; r < RR8; ++r)
                    part[r] += __shfl_xor(part[r], off, 64);
            float Bk = Bn[cc];
            #pragma unroll
            for (int r = 0; r < RR8; ++r) {
                float s = __fsub_rn(__fadd_rn(Ars[r], Bk),
                                    __fmul_rn(2.0f, (float)part[r]));
                if (s < bv[r]) { bv[r] = s; bi[r] = cc; }  // strict < keeps lowest cc
            }
        }
        // cross-group (val, idx) reduce within wave (lanes differ only in g)
        #pragma unroll
        for (int r = 0; r < RR8; ++r) {
            float v = bv[r]; int i1 = bi[r];
            #pragma unroll
            for (int off = 16; off <= 32; off <<= 1) {
                float ov = __shfl_xor(v, off, 64);
                int   oi = __shfl_xor(i1, off, 64);
                if (ov < v || (ov == v && oi < i1)) { v = ov; i1 = oi; }
            }
            if (lane == 0) { wsv[r][w] = v; wsi[r][w] = i1; }
        }
        __syncthreads();
        if (t < nrows) {
            float v = wsv[t][0]; int i1 = wsi[t][0];
            #pragma unroll
            for (int j = 1; j < 8; ++j) {
                float ov = wsv[t][j]; int oi = wsi[t][j];
                if (ov < v || (ov == v && oi < i1)) { v = ov; i1 = oi; }
            }
            idx_out[rid[t]] = (float)i1;
            wbi[t] = i1;
        }
        if (WRITE_OUT) {
            __syncthreads();
            for (int i = t; i < (nrows << 8); i += 512) {
                int r = i >> 8, d = i & 255;
                int n = rid[r];
                outp[(size_t)(n >> 10) * CHW + (size_t)d * HWSZ + (n & 1023)]
                    = emb[(size_t)wbi[r] * DDIM + d];
            }
        }
    }
}

// ---- path B epilogue: gather codebook rows -> out -------------------------
__global__ __launch_bounds__(256) void vq_epilogue(const float* __restrict__ emb,
                                                   float* __restrict__ outp,
                                                   const float* __restrict__ idxf) {
    const int t  = threadIdx.x;
    const int nc = blockIdx.x;
    const int b  = nc >> 4;
    const int hw = ((nc & 15) << 6) + (t & 63);
    const int n  = (b << 10) + hw;
    const int idx = (int)idxf[n];
    const float* erow = emb + (size_t)idx * DDIM;
    const size_t zb = (size_t)b * CHW + hw;

    const int cbase = (t >> 6) << 2;
    #pragma unroll 4
    for (int cq = 0; cq < 16; ++cq) {
        int c = cbase + (cq << 4);
        float4 q4 = *reinterpret_cast<const float4*>(erow + c);
        outp[zb + (size_t)(c + 0) * HWSZ] = q4.x;
        outp[zb + (size_t)(c + 1) * HWSZ] = q4.y;
        outp[zb + (size_t)(c + 2) * HWSZ] = q4.z;
        outp[zb + (size_t)(c + 3) * HWSZ] = q4.w;
    }
}

extern "C" void kernel_launch(void* const* d_in, const int* in_sizes, int n_in,
                              void* d_out, int out_size, void* d_ws, size_t ws_size,
                              hipStream_t stream) {
    const float* z   = (const float*)d_in[0];
    const float* emb = (const float*)d_in[1];
    float* out       = (float*)d_out;
    float* loss_slot = out + LOSS_OFF;
    float* idx_out   = out + IDX_OFF;

    if (ws_size >= (size_t)WS_NEED) {
        // path A: all scratch in ws; out-write fused into argmin + rescore
        char* ws = (char*)d_ws;
        unsigned short* ZHg = (unsigned short*)(ws + WS_ZH);
        unsigned short* EHg = (unsigned short*)(ws + WS_EH);
        unsigned short* ELg = (unsigned short*)(ws + WS_EL);
        float* An = (float*)(ws + WS_AN);
        float* Bn = (float*)(ws + WS_BN);
        int*  list = (int*)(ws + WS_LIST);
        int*  cnt  = (int*)(ws + WS_CNT);

        vq_prep_bn         <<<dim3(16),   dim3(64),  0, stream>>>(emb, Bn, loss_slot, cnt);
        vq_prep_scatter    <<<dim3(128),  dim3(256), 0, stream>>>(emb, EHg, ELg);
        vq_zprep2          <<<dim3(512),  dim3(256), 0, stream>>>(z, ZHg, An);
        vq_argmin2g<true>  <<<dim3(512),  dim3(512), 0, stream>>>(ZHg, EHg, ELg, An, Bn,
                                idx_out, list, cnt, loss_slot, out, emb);
        vq_rescore8<true>  <<<dim3(2048), dim3(512), 0, stream>>>(z, emb, An, Bn,
                                idx_out, list, cnt, out);
    } else {
        // path B: scratch carved from the out region; separate epilogue
        unsigned short* ZHg = (unsigned short*)(out + OB_ZH);
        unsigned short* EHg = (unsigned short*)(out + OB_EH);
        unsigned short* ELg = (unsigned short*)(out + OB_EL);
        float* An = out + OB_AN;
        float* Bn = out + OB_BN;
        int*  list = (int*)(out + OB_LIST);
        int*  cnt  = (int*)(out + OB_CNT);

        vq_prep_bn         <<<dim3(16),   dim3(64),  0, stream>>>(emb, Bn, loss_slot, cnt);
        vq_prep_scatter    <<<dim3(128),  dim3(256), 0, stream>>>(emb, EHg, ELg);
        vq_zprep2          <<<dim3(512),  dim3(256), 0, stream>>>(z, ZHg, An);
        vq_argmin2g<false> <<<dim3(512),  dim3(512), 0, stream>>>(ZHg, EHg, ELg, An, Bn,
                                idx_out, list, cnt, loss_slot, out, emb);
        vq_rescore8<false> <<<dim3(2048), dim3(512), 0, stream>>>(z, emb, An, Bn,
                                idx_out, list, cnt, out);
        vq_epilogue        <<<dim3(1024), dim3(256), 0, stream>>>(emb, out, idx_out);
    }
}

// Round 21
// 218.769 us; speedup vs baseline: 2.1038x; 2.1038x over previous
//
#include <hip/hip_runtime.h>
#include <math.h>

#define KCODES 1024
#define DDIM   256
#define HWSZ   1024
#define CHW    262144
#define LOSS_OFF 16777216
#define IDX_OFF  16777217
#define TAU_GAP  1.4e-4f
#define RR4      4

// ---- path A: ws byte offsets ----
#define WS_ZH   0u          // 33554432 B (32MB)
#define WS_EH   33554432u
#define WS_EL   34078720u
#define WS_AN   34603008u
#define WS_BN   34865152u
#define WS_LIST 34869248u
#define WS_CNT  35131392u
#define WS_NEED 35131396u

// ---- path B: out-region offsets (f32 words) ----
#define OB_ZH   0
#define OB_EH   8388608
#define OB_EL   8519680
#define OB_AN   8650752
#define OB_BN   8716288
#define OB_LIST 8717312
#define OB_CNT  8782848

typedef __attribute__((ext_vector_type(8))) short short8v;
typedef __attribute__((ext_vector_type(4))) float float4v;

// async global->LDS, 16B per lane; LDS dest must be wave-uniform base + lane*16
#define GLOAD_LDS(gsrc, ldst)                                                   \
    __builtin_amdgcn_global_load_lds(                                           \
        (const __attribute__((address_space(1))) void*)(gsrc),                  \
        (__attribute__((address_space(3))) void*)(ldst), 16, 0, 0)

static __device__ __forceinline__ unsigned short bf16_rne(float f) {
    unsigned u = __float_as_uint(f);
    return (unsigned short)((u + 0x7FFFu + ((u >> 16) & 1u)) >> 16);
}
static __device__ __forceinline__ float bf16_tf(unsigned short h) {
    return __uint_as_float(((unsigned)h) << 16);
}

// ---- Bn = ||e_k||^2 (ref pairwise order) + zero cnt/loss ------------------
__global__ __launch_bounds__(64) void vq_prep_bn(const float* __restrict__ emb,
                                                 float* __restrict__ Bn,
                                                 float* __restrict__ loss_slot,
                                                 int* __restrict__ cnt) {
    int k = blockIdx.x * 64 + threadIdx.x;
    if (k == 0) { *cnt = 0; loss_slot[0] = 0.f; }
    if (k >= KCODES) return;
    const float* e = emb + (size_t)k * DDIM;
    float half[2];
    #pragma unroll
    for (int h = 0; h < 2; ++h) {
        const float* q = e + (h << 7);
        float r[8];
        #pragma unroll
        for (int j = 0; j < 8; ++j) r[j] = __fmul_rn(q[j], q[j]);
        for (int i = 8; i < 128; i += 8) {
            #pragma unroll
            for (int j = 0; j < 8; ++j)
                r[j] = __fadd_rn(r[j], __fmul_rn(q[i + j], q[i + j]));
        }
        half[h] = __fadd_rn(
            __fadd_rn(__fadd_rn(r[0], r[1]), __fadd_rn(r[2], r[3])),
            __fadd_rn(__fadd_rn(r[4], r[5]), __fadd_rn(r[6], r[7])));
    }
    Bn[k] = __fadd_rn(half[0], half[1]);
}

// ---- E hi/lo fragment scatter (layout proven r5-r16) ----------------------
__global__ __launch_bounds__(256) void vq_prep_scatter(const float* __restrict__ emb,
                                                       unsigned short* __restrict__ EHg,
                                                       unsigned short* __restrict__ ELg) {
    int task = blockIdx.x * 256 + threadIdx.x;   // 32768 tasks
    int k  = task >> 5;
    int dg = task & 31;
    const float* e = emb + (size_t)k * DDIM + (dg << 3);
    float4 v0 = *(const float4*)e;
    float4 v1 = *(const float4*)(e + 4);
    float f[8] = {v0.x, v0.y, v0.z, v0.w, v1.x, v1.y, v1.z, v1.w};
    short8v hv, lv;
    #pragma unroll
    for (int j = 0; j < 8; ++j) {
        unsigned short hb = bf16_rne(f[j]);
        unsigned short lb = bf16_rne(f[j] - bf16_tf(hb));
        hv[j] = (short)hb; lv[j] = (short)lb;
    }
    int base = ((k >> 4) << 12) + ((dg >> 2) << 9) + (((k & 15) + ((dg & 3) << 4)) << 3);
    *(short8v*)(EHg + base) = hv;
    *(short8v*)(ELg + base) = lv;
}

// ---- fused: An (bit-exact numpy order) + Zh fragment-order pre-convert ----
__global__ __launch_bounds__(256) void vq_zprep2(const float* __restrict__ z,
                                                 unsigned short* __restrict__ ZHg,
                                                 float* __restrict__ An) {
    __shared__ float hs[2][128];
    const int t = threadIdx.x;
    const int nb = blockIdx.x;
    const int b = nb >> 3, hw0 = (nb & 7) << 7;
    const int h = t >> 7, n = t & 127;
    const float* src = z + (size_t)b * CHW + (size_t)(h << 7) * HWSZ + hw0 + n;
    unsigned short* zbase = ZHg + (size_t)nb * 32768 + ((n >> 4) << 9) + ((n & 15) << 3);
    float r[8];
    #pragma unroll
    for (int blk8 = 0; blk8 < 16; ++blk8) {
        float f[8];
        #pragma unroll
        for (int j = 0; j < 8; ++j) f[j] = src[(size_t)((blk8 << 3) + j) * HWSZ];
        if (blk8 == 0) {
            #pragma unroll
            for (int j = 0; j < 8; ++j) r[j] = __fmul_rn(f[j], f[j]);
        } else {
            #pragma unroll
            for (int j = 0; j < 8; ++j) r[j] = __fadd_rn(r[j], __fmul_rn(f[j], f[j]));
        }
        short8v hv;
        #pragma unroll
        for (int j = 0; j < 8; ++j) hv[j] = (short)bf16_rne(f[j]);
        int d = (h << 7) + (blk8 << 3);
        int s32 = d >> 5, g = (d >> 3) & 3;
        *(short8v*)(zbase + s32 * 4096 + (g << 7)) = hv;
    }
    hs[h][n] = __fadd_rn(
        __fadd_rn(__fadd_rn(r[0], r[1]), __fadd_rn(r[2], r[3])),
        __fadd_rn(__fadd_rn(r[4], r[5]), __fadd_rn(r[6], r[7])));
    __syncthreads();
    if (t < 128) An[nb * 128 + t] = __fadd_rn(hs[0][t], hs[1][t]);
}

// ---- main: 2-term MFMA GEMM (Eh+El)xZh + top-2 argmin, 44KB LDS,
//      staging via async global_load_lds (r13/r16 champion, byte-identical) -
template<bool WRITE_OUT>
__global__ __launch_bounds__(512, 4) void vq_argmin2g(
        const unsigned short* __restrict__ ZHg,
        const unsigned short* __restrict__ EHg, const unsigned short* __restrict__ ELg,
        const float* __restrict__ An, const float* __restrict__ Bn,
        float* __restrict__ idx_out, int* __restrict__ list, int* __restrict__ cnt,
        float* __restrict__ loss_slot, float* __restrict__ outp,
        const float* __restrict__ emb) {
    __shared__ uint4 ZH4[512];      // 8 KB: 128n x 32d hi
    __shared__ uint4 EBUF4[2048];   // 32 KB: EH+EL chunk; RED/FIDX alias later
    __shared__ float BNs[1024];     // 4 KB
    unsigned short* ZH = (unsigned short*)ZH4;
    unsigned short* EH = (unsigned short*)EBUF4;
    unsigned short* EL = EH + 8192;

    const int t = threadIdx.x;
    const int bid = blockIdx.x;
    const int nb = ((bid & 7) << 6) + (bid >> 3);   // bijective XCD swizzle
    const int b   = nb >> 3;
    const int hw0 = (nb & 7) << 7;
    const int lane = t & 63, w = t >> 6;
    const int kwv = w >> 1, nwv = w & 1;
    const int l8 = lane << 3, g2 = lane >> 4;

    BNs[t] = Bn[t];
    BNs[t + 512] = Bn[t + 512];

    float an[4];
    #pragma unroll
    for (int nf = 0; nf < 4; ++nf)
        an[nf] = An[nb * 128 + nwv * 64 + nf * 16 + (lane & 15)];

    float mv1[4], mv2[4]; int mi1[4];
    #pragma unroll
    for (int i = 0; i < 4; ++i) { mv1[i] = 3.4e38f; mv2[i] = 3.4e38f; mi1[i] = 0x7fffffff; }

    const uint4* zh4 = (const uint4*)ZHg + (size_t)nb * 4096;
    const uint4* eh4 = (const uint4*)EHg;
    const uint4* el4 = (const uint4*)ELg;

    for (int kt = 0; kt < 4; ++kt) {
        float4v acc[4][4];
        #pragma unroll
        for (int a = 0; a < 4; ++a)
            #pragma unroll
            for (int c = 0; c < 4; ++c) acc[a][c] = (float4v){0.f, 0.f, 0.f, 0.f};

        for (int s32 = 0; s32 < 8; ++s32) {
            __syncthreads();                 // prior readers done
            GLOAD_LDS(zh4 + s32 * 512 + t, &ZH4[t]);
            #pragma unroll
            for (int p = 0; p < 4; ++p) {
                int s = p * 512 + t;
                int arr = s >> 10, ss = s & 1023;
                const uint4* src = (arr ? el4 : eh4)
                    + (size_t)(((kt << 4) + (ss >> 6)) << 9) + (s32 << 6) + (ss & 63);
                uint4* dst = (arr ? ((uint4*)EL) : ((uint4*)EH)) + ss;
                GLOAD_LDS(src, dst);
            }
            __syncthreads();                 // vmcnt(0) drain: staging visible
            short8v ah[4], al[4], bh[4];
            #pragma unroll
            for (int kf = 0; kf < 4; ++kf) {
                int base = ((kwv * 4 + kf) << 9) + l8;
                ah[kf] = *(const short8v*)&EH[base];
                al[kf] = *(const short8v*)&EL[base];
            }
            #pragma unroll
            for (int nf = 0; nf < 4; ++nf)
                bh[nf] = *(const short8v*)&ZH[((nwv * 4 + nf) << 9) + l8];
            #pragma unroll
            for (int kf = 0; kf < 4; ++kf)
                #pragma unroll
                for (int nf = 0; nf < 4; ++nf) {
                    acc[kf][nf] = __builtin_amdgcn_mfma_f32_16x16x32_bf16(ah[kf], bh[nf], acc[kf][nf], 0, 0, 0);
                    acc[kf][nf] = __builtin_amdgcn_mfma_f32_16x16x32_bf16(al[kf], bh[nf], acc[kf][nf], 0, 0, 0);
                }
        }
        #pragma unroll
        for (int kf = 0; kf < 4; ++kf)
            #pragma unroll
            for (int nf = 0; nf < 4; ++nf)
                #pragma unroll
                for (int r = 0; r < 4; ++r) {
                    int k = kt * 256 + kwv * 64 + kf * 16 + g2 * 4 + r;
                    float s = __fsub_rn(__fadd_rn(an[nf], BNs[k]),
                                        __fmul_rn(2.0f, acc[kf][nf][r]));
                    if (s < mv1[nf] || (s == mv1[nf] && k < mi1[nf])) {
                        mv2[nf] = fminf(mv2[nf], mv1[nf]);
                        mv1[nf] = s; mi1[nf] = k;
                    } else if (s < mv2[nf]) mv2[nf] = s;
                }
    }

    __syncthreads();   // E done -> alias EBUF as RED/FIDX
    float* REDv = (float*)EBUF4;
    int*   REDi = (int*)((char*)EBUF4 + 8192);
    float* REDw = (float*)((char*)EBUF4 + 16384);
    int*   FIDX = (int*)((char*)EBUF4 + 24576);

    #pragma unroll
    for (int nf = 0; nf < 4; ++nf) {
        int nl = nf * 16 + (lane & 15);
        int slot = kwv * 4 + g2;
        REDv[(nwv * 64 + nl) * 16 + slot] = mv1[nf];
        REDi[(nwv * 64 + nl) * 16 + slot] = mi1[nf];
        REDw[(nwv * 64 + nl) * 16 + slot] = mv2[nf];
    }
    __syncthreads();
    if (t < 128) {
        float bv = 3.4e38f, b2 = 3.4e38f; int bi = 0x7fffffff;
        #pragma unroll
        for (int s = 0; s < 16; ++s) {
            float v1 = REDv[t * 16 + s];
            float v2 = REDw[t * 16 + s];
            int   i1 = REDi[t * 16 + s];
            if (v1 < bv || (v1 == bv && i1 < bi)) { b2 = fminf(b2, bv); bv = v1; bi = i1; }
            else b2 = fminf(b2, v1);
            b2 = fminf(b2, v2);
        }
        int n_glob = nb * 128 + t;
        idx_out[n_glob] = (float)bi;
        FIDX[t] = bi;
        if (b2 - bv < TAU_GAP) {
            int pos = atomicAdd(cnt, 1);
            list[pos] = n_glob;
        }
        float lsum = bv;
        #pragma unroll
        for (int off = 32; off > 0; off >>= 1)
            lsum += __shfl_down(lsum, off, 64);
        if ((t & 63) == 0) atomicAdd(loss_slot, lsum * (1.25f / 16777216.f));
    }
    if (WRITE_OUT) {
        __syncthreads();
        int n_loc = t & 127, cg = t >> 7;
        int idx = FIDX[n_loc];
        int hw = hw0 + n_loc;
        const float4* erow = (const float4*)(emb + (size_t)idx * DDIM + (cg << 6));
        float* obase = outp + (size_t)b * CHW + (size_t)(cg << 6) * HWSZ + hw;
        #pragma unroll 4
        for (int q = 0; q < 16; ++q) {
            float4 v = erow[q];
            obase[(size_t)(q * 4 + 0) * HWSZ] = v.x;
            obase[(size_t)(q * 4 + 1) * HWSZ] = v.y;
            obase[(size_t)(q * 4 + 2) * HWSZ] = v.z;
            obase[(size_t)(q * 4 + 3) * HWSZ] = v.w;
        }
    }
}

// ---- coalesced f64 rescore: 16-lane group per code, lanes split d ---------
template<bool WRITE_OUT>
__global__ __launch_bounds__(512) void vq_rescore_c(
        const float* __restrict__ z, const float* __restrict__ emb,
        const float* __restrict__ An, const float* __restrict__ Bn,
        float* __restrict__ idx_out, const int* __restrict__ list,
        const int* __restrict__ cnt, float* __restrict__ outp) {
    const int c = *cnt;
    const int t = threadIdx.x;
    const int lane = t & 63, w = t >> 6;   // 8 waves
    const int g  = lane >> 4;              // group 0..3 (one code each)
    const int ch = lane & 15;              // d-chunk within group
    __shared__ float zs[RR4][256];
    __shared__ float Ars[RR4];
    __shared__ int   rid[RR4];
    __shared__ float wsv[RR4][8];
    __shared__ int   wsi[RR4][8];
    __shared__ int   wbi[RR4];

    for (int base = blockIdx.x * RR4; base < c; base += gridDim.x * RR4) {
        const int nrows = min(RR4, c - base);
        __syncthreads();
        if (t < nrows) { int n = list[base + t]; rid[t] = n; Ars[t] = An[n]; }
        __syncthreads();
        for (int i = t; i < (nrows << 8); i += 512) {
            int r = i >> 8, d = i & 255;
            int n = rid[r];
            zs[r][d] = z[(size_t)(n >> 10) * CHW + (size_t)d * HWSZ + (n & 1023)];
        }
        __syncthreads();

        float bv[RR4]; int bi[RR4];
        #pragma unroll
        for (int r = 0; r < RR4; ++r) { bv[r] = 3.4e38f; bi[r] = 0x7fffffff; }

        for (int p = 0; p < 32; ++p) {          // ascending codes
            int cc = p * 32 + w * 4 + g;
            const float4* e4 = (const float4*)(emb + (size_t)cc * DDIM);
            double part[RR4];
            #pragma unroll
            for (int r = 0; r < RR4; ++r) part[r] = 0.0;
            #pragma unroll
            for (int it = 0; it < 4; ++it) {
                float4 ev = e4[it * 16 + ch];   // 256B dense per group
                #pragma unroll
                for (int r = 0; r < RR4; ++r) {
                    float4 zv = *(const float4*)&zs[r][(it * 16 + ch) << 2];
                    part[r] += (double)ev.x * zv.x + (double)ev.y * zv.y
                             + (double)ev.z * zv.z + (double)ev.w * zv.w;
                }
            }
            // 16-lane group sum (xor butterfly, f64)
            #pragma unroll
            for (int off = 1; off <= 8; off <<= 1)
                #pragma unroll
                for (int r = 0; r < RR4; ++r)
                    part[r] += __shfl_xor(part[r], off, 64);
            float Bk = Bn[cc];
            #pragma unroll
            for (int r = 0; r < RR4; ++r) {
                float s = __fsub_rn(__fadd_rn(Ars[r], Bk),
                                    __fmul_rn(2.0f, (float)part[r]));
                if (s < bv[r]) { bv[r] = s; bi[r] = cc; }  // strict < keeps lowest cc
            }
        }
        // cross-group (val, idx) reduce within wave (lanes differ only in g)
        #pragma unroll
        for (int r = 0; r < RR4; ++r) {
            float v = bv[r]; int i1 = bi[r];
            #pragma unroll
            for (int off = 16; off <= 32; off <<= 1) {
                float ov = __shfl_xor(v, off, 64);
                int   oi = __shfl_xor(i1, off, 64);
                if (ov < v || (ov == v && oi < i1)) { v = ov; i1 = oi; }
            }
            if (lane == 0) { wsv[r][w] = v; wsi[r][w] = i1; }
        }
        __syncthreads();
        if (t < nrows) {
            float v = wsv[t][0]; int i1 = wsi[t][0];
            #pragma unroll
            for (int j = 1; j < 8; ++j) {
                float ov = wsv[t][j]; int oi = wsi[t][j];
                if (ov < v || (ov == v && oi < i1)) { v = ov; i1 = oi; }
            }
            idx_out[rid[t]] = (float)i1;
            wbi[t] = i1;
        }
        if (WRITE_OUT) {
            __syncthreads();
            for (int i = t; i < (nrows << 8); i += 512) {
                int r = i >> 8, d = i & 255;
                int n = rid[r];
                outp[(size_t)(n >> 10) * CHW + (size_t)d * HWSZ + (n & 1023)]
                    = emb[(size_t)wbi[r] * DDIM + d];
            }
        }
    }
}

// ---- path B epilogue: gather codebook rows -> out -------------------------
__global__ __launch_bounds__(256) void vq_epilogue(const float* __restrict__ emb,
                                                   float* __restrict__ outp,
                                                   const float* __restrict__ idxf) {
    const int t  = threadIdx.x;
    const int nc = blockIdx.x;
    const int b  = nc >> 4;
    const int hw = ((nc & 15) << 6) + (t & 63);
    const int n  = (b << 10) + hw;
    const int idx = (int)idxf[n];
    const float* erow = emb + (size_t)idx * DDIM;
    const size_t zb = (size_t)b * CHW + hw;

    const int cbase = (t >> 6) << 2;
    #pragma unroll 4
    for (int cq = 0; cq < 16; ++cq) {
        int c = cbase + (cq << 4);
        float4 q4 = *reinterpret_cast<const float4*>(erow + c);
        outp[zb + (size_t)(c + 0) * HWSZ] = q4.x;
        outp[zb + (size_t)(c + 1) * HWSZ] = q4.y;
        outp[zb + (size_t)(c + 2) * HWSZ] = q4.z;
        outp[zb + (size_t)(c + 3) * HWSZ] = q4.w;
    }
}

extern "C" void kernel_launch(void* const* d_in, const int* in_sizes, int n_in,
                              void* d_out, int out_size, void* d_ws, size_t ws_size,
                              hipStream_t stream) {
    const float* z   = (const float*)d_in[0];
    const float* emb = (const float*)d_in[1];
    float* out       = (float*)d_out;
    float* loss_slot = out + LOSS_OFF;
    float* idx_out   = out + IDX_OFF;

    if (ws_size >= (size_t)WS_NEED) {
        // path A: all scratch in ws; out-write fused into argmin + rescore
        char* ws = (char*)d_ws;
        unsigned short* ZHg = (unsigned short*)(ws + WS_ZH);
        unsigned short* EHg = (unsigned short*)(ws + WS_EH);
        unsigned short* ELg = (unsigned short*)(ws + WS_EL);
        float* An = (float*)(ws + WS_AN);
        float* Bn = (float*)(ws + WS_BN);
        int*  list = (int*)(ws + WS_LIST);
        int*  cnt  = (int*)(ws + WS_CNT);

        vq_prep_bn          <<<dim3(16),   dim3(64),  0, stream>>>(emb, Bn, loss_slot, cnt);
        vq_prep_scatter     <<<dim3(128),  dim3(256), 0, stream>>>(emb, EHg, ELg);
        vq_zprep2           <<<dim3(512),  dim3(256), 0, stream>>>(z, ZHg, An);
        vq_argmin2g<true>   <<<dim3(512),  dim3(512), 0, stream>>>(ZHg, EHg, ELg, An, Bn,
                                 idx_out, list, cnt, loss_slot, out, emb);
        vq_rescore_c<true>  <<<dim3(2048), dim3(512), 0, stream>>>(z, emb, An, Bn,
                                 idx_out, list, cnt, out);
    } else {
        // path B: scratch carved from the out region; separate epilogue
        unsigned short* ZHg = (unsigned short*)(out + OB_ZH);
        unsigned short* EHg = (unsigned short*)(out + OB_EH);
        unsigned short* ELg = (unsigned short*)(out + OB_EL);
        float* An = out + OB_AN;
        float* Bn = out + OB_BN;
        int*  list = (int*)(out + OB_LIST);
        int*  cnt  = (int*)(out + OB_CNT);

        vq_prep_bn          <<<dim3(16),   dim3(64),  0, stream>>>(emb, Bn, loss_slot, cnt);
        vq_prep_scatter     <<<dim3(128),  dim3(256), 0, stream>>>(emb, EHg, ELg);
        vq_zprep2           <<<dim3(512),  dim3(256), 0, stream>>>(z, ZHg, An);
        vq_argmin2g<false>  <<<dim3(512),  dim3(512), 0, stream>>>(ZHg, EHg, ELg, An, Bn,
                                 idx_out, list, cnt, loss_slot, out, emb);
        vq_rescore_c<false> <<<dim3(2048), dim3(512), 0, stream>>>(z, emb, An, Bn,
                                 idx_out, list, cnt, out);
        vq_epilogue         <<<dim3(1024), dim3(256), 0, stream>>>(emb, out, idx_out);
    }
}

// Round 22
// 208.670 us; speedup vs baseline: 2.2056x; 1.0484x over previous
//
#include <hip/hip_runtime.h>
#include <math.h>

#define KCODES 1024
#define DDIM   256
#define HWSZ   1024
#define CHW    262144
#define LOSS_OFF 16777216
#define IDX_OFF  16777217
#define TAU_GAP  1.4e-4f
#define RR4      4

// ---- path A: ws byte offsets ----
#define WS_ZH   0u          // 33554432 B (32MB)
#define WS_EH   33554432u
#define WS_EL   34078720u
#define WS_AN   34603008u
#define WS_BN   34865152u
#define WS_LIST 34869248u
#define WS_CNT  35131392u
#define WS_NEED 35131396u

// ---- path B: out-region offsets (f32 words) ----
#define OB_ZH   0
#define OB_EH   8388608
#define OB_EL   8519680
#define OB_AN   8650752
#define OB_BN   8716288
#define OB_LIST 8717312
#define OB_CNT  8782848

typedef __attribute__((ext_vector_type(8))) short short8v;
typedef __attribute__((ext_vector_type(4))) float float4v;

// async global->LDS, 16B per lane; LDS dest must be wave-uniform base + lane*16
#define GLOAD_LDS(gsrc, ldst)                                                   \
    __builtin_amdgcn_global_load_lds(                                           \
        (const __attribute__((address_space(1))) void*)(gsrc),                  \
        (__attribute__((address_space(3))) void*)(ldst), 16, 0, 0)

static __device__ __forceinline__ unsigned short bf16_rne(float f) {
    unsigned u = __float_as_uint(f);
    return (unsigned short)((u + 0x7FFFu + ((u >> 16) & 1u)) >> 16);
}
static __device__ __forceinline__ float bf16_tf(unsigned short h) {
    return __uint_as_float(((unsigned)h) << 16);
}

// ---- Bn = ||e_k||^2 (ref pairwise order) + zero cnt/loss ------------------
__global__ __launch_bounds__(64) void vq_prep_bn(const float* __restrict__ emb,
                                                 float* __restrict__ Bn,
                                                 float* __restrict__ loss_slot,
                                                 int* __restrict__ cnt) {
    int k = blockIdx.x * 64 + threadIdx.x;
    if (k == 0) { *cnt = 0; loss_slot[0] = 0.f; }
    if (k >= KCODES) return;
    const float* e = emb + (size_t)k * DDIM;
    float half[2];
    #pragma unroll
    for (int h = 0; h < 2; ++h) {
        const float* q = e + (h << 7);
        float r[8];
        #pragma unroll
        for (int j = 0; j < 8; ++j) r[j] = __fmul_rn(q[j], q[j]);
        for (int i = 8; i < 128; i += 8) {
            #pragma unroll
            for (int j = 0; j < 8; ++j)
                r[j] = __fadd_rn(r[j], __fmul_rn(q[i + j], q[i + j]));
        }
        half[h] = __fadd_rn(
            __fadd_rn(__fadd_rn(r[0], r[1]), __fadd_rn(r[2], r[3])),
            __fadd_rn(__fadd_rn(r[4], r[5]), __fadd_rn(r[6], r[7])));
    }
    Bn[k] = __fadd_rn(half[0], half[1]);
}

// ---- E hi/lo fragment scatter (layout proven r5-r21) ----------------------
__global__ __launch_bounds__(256) void vq_prep_scatter(const float* __restrict__ emb,
                                                       unsigned short* __restrict__ EHg,
                                                       unsigned short* __restrict__ ELg) {
    int task = blockIdx.x * 256 + threadIdx.x;   // 32768 tasks
    int k  = task >> 5;
    int dg = task & 31;
    const float* e = emb + (size_t)k * DDIM + (dg << 3);
    float4 v0 = *(const float4*)e;
    float4 v1 = *(const float4*)(e + 4);
    float f[8] = {v0.x, v0.y, v0.z, v0.w, v1.x, v1.y, v1.z, v1.w};
    short8v hv, lv;
    #pragma unroll
    for (int j = 0; j < 8; ++j) {
        unsigned short hb = bf16_rne(f[j]);
        unsigned short lb = bf16_rne(f[j] - bf16_tf(hb));
        hv[j] = (short)hb; lv[j] = (short)lb;
    }
    int base = ((k >> 4) << 12) + ((dg >> 2) << 9) + (((k & 15) + ((dg & 3) << 4)) << 3);
    *(short8v*)(EHg + base) = hv;
    *(short8v*)(ELg + base) = lv;
}

// ---- fused main: zprep prologue (bit-exact An + Zh scatter via L2) +
//      champion 2-term MFMA GEMM + top-2 argmin -----------------------------
template<bool WRITE_OUT>
__global__ __launch_bounds__(512, 4) void vq_argmin2gf(
        const float* __restrict__ z, unsigned short* __restrict__ ZHg,
        const unsigned short* __restrict__ EHg, const unsigned short* __restrict__ ELg,
        float* __restrict__ Ang, const float* __restrict__ Bn,
        float* __restrict__ idx_out, int* __restrict__ list, int* __restrict__ cnt,
        float* __restrict__ loss_slot, float* __restrict__ outp,
        const float* __restrict__ emb) {
    __shared__ uint4 ZH4[512];      // 8 KB: 128n x 32d hi chunk
    __shared__ uint4 EBUF4[2048];   // 32 KB: EH+EL chunk; RED/FIDX alias later
    __shared__ float BNs[1024];     // 4 KB
    __shared__ float hs[2][128];
    __shared__ float ANs[128];
    unsigned short* ZH = (unsigned short*)ZH4;
    unsigned short* EH = (unsigned short*)EBUF4;
    unsigned short* EL = EH + 8192;

    const int t = threadIdx.x;
    const int bid = blockIdx.x;
    const int nb = ((bid & 7) << 6) + (bid >> 3);   // bijective XCD swizzle
    const int b   = nb >> 3;
    const int hw0 = (nb & 7) << 7;
    const int lane = t & 63, w = t >> 6;
    const int kwv = w >> 1, nwv = w & 1;
    const int l8 = lane << 3, g2 = lane >> 4;

    // ---- prologue: zprep2 body (bit-exact An + Zh fragment scatter) ----
    if (t < 256) {
        const int h = t >> 7, n = t & 127;
        const float* src = z + (size_t)b * CHW + (size_t)(h << 7) * HWSZ + hw0 + n;
        unsigned short* zbase = ZHg + (size_t)nb * 32768 + ((n >> 4) << 9) + ((n & 15) << 3);
        float r[8];
        #pragma unroll
        for (int blk8 = 0; blk8 < 16; ++blk8) {
            float f[8];
            #pragma unroll
            for (int j = 0; j < 8; ++j) f[j] = src[(size_t)((blk8 << 3) + j) * HWSZ];
            if (blk8 == 0) {
                #pragma unroll
                for (int j = 0; j < 8; ++j) r[j] = __fmul_rn(f[j], f[j]);
            } else {
                #pragma unroll
                for (int j = 0; j < 8; ++j) r[j] = __fadd_rn(r[j], __fmul_rn(f[j], f[j]));
            }
            short8v hv;
            #pragma unroll
            for (int j = 0; j < 8; ++j) hv[j] = (short)bf16_rne(f[j]);
            int d = (h << 7) + (blk8 << 3);
            int s32 = d >> 5, g = (d >> 3) & 3;
            *(short8v*)(zbase + s32 * 4096 + (g << 7)) = hv;
        }
        hs[h][n] = __fadd_rn(
            __fadd_rn(__fadd_rn(r[0], r[1]), __fadd_rn(r[2], r[3])),
            __fadd_rn(__fadd_rn(r[4], r[5]), __fadd_rn(r[6], r[7])));
    } else {
        const int t2 = t - 256;
        #pragma unroll
        for (int p = 0; p < 4; ++p) BNs[p * 256 + t2] = Bn[p * 256 + t2];
    }
    __syncthreads();                 // ZHg writes drained (vmcnt0) + hs visible
    if (t < 128) {
        float a = __fadd_rn(hs[0][t], hs[1][t]);
        ANs[t] = a;
        Ang[nb * 128 + t] = a;       // rescore reads this from global
    }
    __syncthreads();

    float an[4];
    #pragma unroll
    for (int nf = 0; nf < 4; ++nf)
        an[nf] = ANs[nwv * 64 + nf * 16 + (lane & 15)];

    float mv1[4], mv2[4]; int mi1[4];
    #pragma unroll
    for (int i = 0; i < 4; ++i) { mv1[i] = 3.4e38f; mv2[i] = 3.4e38f; mi1[i] = 0x7fffffff; }

    const uint4* zh4 = (const uint4*)ZHg + (size_t)nb * 4096;
    const uint4* eh4 = (const uint4*)EHg;
    const uint4* el4 = (const uint4*)ELg;

    // ---- champion main loop (byte-identical to r16/r21) ----
    for (int kt = 0; kt < 4; ++kt) {
        float4v acc[4][4];
        #pragma unroll
        for (int a = 0; a < 4; ++a)
            #pragma unroll
            for (int c = 0; c < 4; ++c) acc[a][c] = (float4v){0.f, 0.f, 0.f, 0.f};

        for (int s32 = 0; s32 < 8; ++s32) {
            __syncthreads();                 // prior readers done
            GLOAD_LDS(zh4 + s32 * 512 + t, &ZH4[t]);
            #pragma unroll
            for (int p = 0; p < 4; ++p) {
                int s = p * 512 + t;
                int arr = s >> 10, ss = s & 1023;
                const uint4* src = (arr ? el4 : eh4)
                    + (size_t)(((kt << 4) + (ss >> 6)) << 9) + (s32 << 6) + (ss & 63);
                uint4* dst = (arr ? ((uint4*)EL) : ((uint4*)EH)) + ss;
                GLOAD_LDS(src, dst);
            }
            __syncthreads();                 // vmcnt(0) drain: staging visible
            short8v ah[4], al[4], bh[4];
            #pragma unroll
            for (int kf = 0; kf < 4; ++kf) {
                int base = ((kwv * 4 + kf) << 9) + l8;
                ah[kf] = *(const short8v*)&EH[base];
                al[kf] = *(const short8v*)&EL[base];
            }
            #pragma unroll
            for (int nf = 0; nf < 4; ++nf)
                bh[nf] = *(const short8v*)&ZH[((nwv * 4 + nf) << 9) + l8];
            #pragma unroll
            for (int kf = 0; kf < 4; ++kf)
                #pragma unroll
                for (int nf = 0; nf < 4; ++nf) {
                    acc[kf][nf] = __builtin_amdgcn_mfma_f32_16x16x32_bf16(ah[kf], bh[nf], acc[kf][nf], 0, 0, 0);
                    acc[kf][nf] = __builtin_amdgcn_mfma_f32_16x16x32_bf16(al[kf], bh[nf], acc[kf][nf], 0, 0, 0);
                }
        }
        #pragma unroll
        for (int kf = 0; kf < 4; ++kf)
            #pragma unroll
            for (int nf = 0; nf < 4; ++nf)
                #pragma unroll
                for (int r = 0; r < 4; ++r) {
                    int k = kt * 256 + kwv * 64 + kf * 16 + g2 * 4 + r;
                    float s = __fsub_rn(__fadd_rn(an[nf], BNs[k]),
                                        __fmul_rn(2.0f, acc[kf][nf][r]));
                    if (s < mv1[nf] || (s == mv1[nf] && k < mi1[nf])) {
                        mv2[nf] = fminf(mv2[nf], mv1[nf]);
                        mv1[nf] = s; mi1[nf] = k;
                    } else if (s < mv2[nf]) mv2[nf] = s;
                }
    }

    __syncthreads();   // E done -> alias EBUF as RED/FIDX
    float* REDv = (float*)EBUF4;
    int*   REDi = (int*)((char*)EBUF4 + 8192);
    float* REDw = (float*)((char*)EBUF4 + 16384);
    int*   FIDX = (int*)((char*)EBUF4 + 24576);

    #pragma unroll
    for (int nf = 0; nf < 4; ++nf) {
        int nl = nf * 16 + (lane & 15);
        int slot = kwv * 4 + g2;
        REDv[(nwv * 64 + nl) * 16 + slot] = mv1[nf];
        REDi[(nwv * 64 + nl) * 16 + slot] = mi1[nf];
        REDw[(nwv * 64 + nl) * 16 + slot] = mv2[nf];
    }
    __syncthreads();
    if (t < 128) {
        float bv = 3.4e38f, b2 = 3.4e38f; int bi = 0x7fffffff;
        #pragma unroll
        for (int s = 0; s < 16; ++s) {
            float v1 = REDv[t * 16 + s];
            float v2 = REDw[t * 16 + s];
            int   i1 = REDi[t * 16 + s];
            if (v1 < bv || (v1 == bv && i1 < bi)) { b2 = fminf(b2, bv); bv = v1; bi = i1; }
            else b2 = fminf(b2, v1);
            b2 = fminf(b2, v2);
        }
        int n_glob = nb * 128 + t;
        idx_out[n_glob] = (float)bi;
        FIDX[t] = bi;
        if (b2 - bv < TAU_GAP) {
            int pos = atomicAdd(cnt, 1);
            list[pos] = n_glob;
        }
        float lsum = bv;
        #pragma unroll
        for (int off = 32; off > 0; off >>= 1)
            lsum += __shfl_down(lsum, off, 64);
        if ((t & 63) == 0) atomicAdd(loss_slot, lsum * (1.25f / 16777216.f));
    }
    if (WRITE_OUT) {
        __syncthreads();
        int n_loc = t & 127, cg = t >> 7;
        int idx = FIDX[n_loc];
        int hw = hw0 + n_loc;
        const float4* erow = (const float4*)(emb + (size_t)idx * DDIM + (cg << 6));
        float* obase = outp + (size_t)b * CHW + (size_t)(cg << 6) * HWSZ + hw;
        #pragma unroll 4
        for (int q = 0; q < 16; ++q) {
            float4 v = erow[q];
            obase[(size_t)(q * 4 + 0) * HWSZ] = v.x;
            obase[(size_t)(q * 4 + 1) * HWSZ] = v.y;
            obase[(size_t)(q * 4 + 2) * HWSZ] = v.z;
            obase[(size_t)(q * 4 + 3) * HWSZ] = v.w;
        }
    }
}

// ---- coalesced f64 rescore: 16-lane group per code, lanes split d ---------
template<bool WRITE_OUT>
__global__ __launch_bounds__(512) void vq_rescore_c(
        const float* __restrict__ z, const float* __restrict__ emb,
        const float* __restrict__ An, const float* __restrict__ Bn,
        float* __restrict__ idx_out, const int* __restrict__ list,
        const int* __restrict__ cnt, float* __restrict__ outp) {
    const int c = *cnt;
    const int t = threadIdx.x;
    const int lane = t & 63, w = t >> 6;   // 8 waves
    const int g  = lane >> 4;              // group 0..3 (one code each)
    const int ch = lane & 15;              // d-chunk within group
    __shared__ float zs[RR4][256];
    __shared__ float Ars[RR4];
    __shared__ int   rid[RR4];
    __shared__ float wsv[RR4][8];
    __shared__ int   wsi[RR4][8];
    __shared__ int   wbi[RR4];

    for (int base = blockIdx.x * RR4; base < c; base += gridDim.x * RR4) {
        const int nrows = min(RR4, c - base);
        __syncthreads();
        if (t < nrows) { int n = list[base + t]; rid[t] = n; Ars[t] = An[n]; }
        __syncthreads();
        for (int i = t; i < (nrows << 8); i += 512) {
            int r = i >> 8, d = i & 255;
            int n = rid[r];
            zs[r][d] = z[(size_t)(n >> 10) * CHW + (size_t)d * HWSZ + (n & 1023)];
        }
        __syncthreads();

        float bv[RR4]; int bi[RR4];
        #pragma unroll
        for (int r = 0; r < RR4; ++r) { bv[r] = 3.4e38f; bi[r] = 0x7fffffff; }

        for (int p = 0; p < 32; ++p) {          // ascending codes
            int cc = p * 32 + w * 4 + g;
            const float4* e4 = (const float4*)(emb + (size_t)cc * DDIM);
            double part[RR4];
            #pragma unroll
            for (int r = 0; r < RR4; ++r) part[r] = 0.0;
            #pragma unroll
            for (int it = 0; it < 4; ++it) {
                float4 ev = e4[it * 16 + ch];   // 256B dense per group
                #pragma unroll
                for (int r = 0; r < RR4; ++r) {
                    float4 zv = *(const float4*)&zs[r][(it * 16 + ch) << 2];
                    part[r] += (double)ev.x * zv.x + (double)ev.y * zv.y
                             + (double)ev.z * zv.z + (double)ev.w * zv.w;
                }
            }
            // 16-lane group sum (xor butterfly, f64)
            #pragma unroll
            for (int off = 1; off <= 8; off <<= 1)
                #pragma unroll
                for (int r = 0; r < RR4; ++r)
                    part[r] += __shfl_xor(part[r], off, 64);
            float Bk = Bn[cc];
            #pragma unroll
            for (int r = 0; r < RR4; ++r) {
                float s = __fsub_rn(__fadd_rn(Ars[r], Bk),
                                    __fmul_rn(2.0f, (float)part[r]));
                if (s < bv[r]) { bv[r] = s; bi[r] = cc; }  // strict < keeps lowest cc
            }
        }
        // cross-group (val, idx) reduce within wave (lanes differ only in g)
        #pragma unroll
        for (int r = 0; r < RR4; ++r) {
            float v = bv[r]; int i1 = bi[r];
            #pragma unroll
            for (int off = 16; off <= 32; off <<= 1) {
                float ov = __shfl_xor(v, off, 64);
                int   oi = __shfl_xor(i1, off, 64);
                if (ov < v || (ov == v && oi < i1)) { v = ov; i1 = oi; }
            }
            if (lane == 0) { wsv[r][w] = v; wsi[r][w] = i1; }
        }
        __syncthreads();
        if (t < nrows) {
            float v = wsv[t][0]; int i1 = wsi[t][0];
            #pragma unroll
            for (int j = 1; j < 8; ++j) {
                float ov = wsv[t][j]; int oi = wsi[t][j];
                if (ov < v || (ov == v && oi < i1)) { v = ov; i1 = oi; }
            }
            idx_out[rid[t]] = (float)i1;
            wbi[t] = i1;
        }
        if (WRITE_OUT) {
            __syncthreads();
            for (int i = t; i < (nrows << 8); i += 512) {
                int r = i >> 8, d = i & 255;
                int n = rid[r];
                outp[(size_t)(n >> 10) * CHW + (size_t)d * HWSZ + (n & 1023)]
                    = emb[(size_t)wbi[r] * DDIM + d];
            }
        }
    }
}

// ---- path B epilogue: gather codebook rows -> out -------------------------
__global__ __launch_bounds__(256) void vq_epilogue(const float* __restrict__ emb,
                                                   float* __restrict__ outp,
                                                   const float* __restrict__ idxf) {
    const int t  = threadIdx.x;
    const int nc = blockIdx.x;
    const int b  = nc >> 4;
    const int hw = ((nc & 15) << 6) + (t & 63);
    const int n  = (b << 10) + hw;
    const int idx = (int)idxf[n];
    const float* erow = emb + (size_t)idx * DDIM;
    const size_t zb = (size_t)b * CHW + hw;

    const int cbase = (t >> 6) << 2;
    #pragma unroll 4
    for (int cq = 0; cq < 16; ++cq) {
        int c = cbase + (cq << 4);
        float4 q4 = *reinterpret_cast<const float4*>(erow + c);
        outp[zb + (size_t)(c + 0) * HWSZ] = q4.x;
        outp[zb + (size_t)(c + 1) * HWSZ] = q4.y;
        outp[zb + (size_t)(c + 2) * HWSZ] = q4.z;
        outp[zb + (size_t)(c + 3) * HWSZ] = q4.w;
    }
}

extern "C" void kernel_launch(void* const* d_in, const int* in_sizes, int n_in,
                              void* d_out, int out_size, void* d_ws, size_t ws_size,
                              hipStream_t stream) {
    const float* z   = (const float*)d_in[0];
    const float* emb = (const float*)d_in[1];
    float* out       = (float*)d_out;
    float* loss_slot = out + LOSS_OFF;
    float* idx_out   = out + IDX_OFF;

    if (ws_size >= (size_t)WS_NEED) {
        // path A: all scratch in ws; zprep fused into argmin prologue
        char* ws = (char*)d_ws;
        unsigned short* ZHg = (unsigned short*)(ws + WS_ZH);
        unsigned short* EHg = (unsigned short*)(ws + WS_EH);
        unsigned short* ELg = (unsigned short*)(ws + WS_EL);
        float* An = (float*)(ws + WS_AN);
        float* Bn = (float*)(ws + WS_BN);
        int*  list = (int*)(ws + WS_LIST);
        int*  cnt  = (int*)(ws + WS_CNT);

        vq_prep_bn          <<<dim3(16),   dim3(64),  0, stream>>>(emb, Bn, loss_slot, cnt);
        vq_prep_scatter     <<<dim3(128),  dim3(256), 0, stream>>>(emb, EHg, ELg);
        vq_argmin2gf<true>  <<<dim3(512),  dim3(512), 0, stream>>>(z, ZHg, EHg, ELg, An, Bn,
                                 idx_out, list, cnt, loss_slot, out, emb);
        vq_rescore_c<true>  <<<dim3(2048), dim3(512), 0, stream>>>(z, emb, An, Bn,
                                 idx_out, list, cnt, out);
    } else {
        // path B: scratch carved from the out region; separate epilogue
        unsigned short* ZHg = (unsigned short*)(out + OB_ZH);
        unsigned short* EHg = (unsigned short*)(out + OB_EH);
        unsigned short* ELg = (unsigned short*)(out + OB_EL);
        float* An = out + OB_AN;
        float* Bn = out + OB_BN;
        int*  list = (int*)(out + OB_LIST);
        int*  cnt  = (int*)(out + OB_CNT);

        vq_prep_bn          <<<dim3(16),   dim3(64),  0, stream>>>(emb, Bn, loss_slot, cnt);
        vq_prep_scatter     <<<dim3(128),  dim3(256), 0, stream>>>(emb, EHg, ELg);
        vq_argmin2gf<false> <<<dim3(512),  dim3(512), 0, stream>>>(z, ZHg, EHg, ELg, An, Bn,
                                 idx_out, list, cnt, loss_slot, out, emb);
        vq_rescore_c<false> <<<dim3(2048), dim3(512), 0, stream>>>(z, emb, An, Bn,
                                 idx_out, list, cnt, out);
        vq_epilogue         <<<dim3(1024), dim3(256), 0, stream>>>(emb, out, idx_out);
    }
}